// Round 10
// baseline (134.505 us; speedup 1.0000x reference)
//
#include <hip/hip_runtime.h>

typedef __attribute__((ext_vector_type(8))) short bf16x8;
typedef __attribute__((ext_vector_type(4))) float f32x4;

#define MDIM 256
#define NDIM 4096
#define KDIM 4096
#define KP8 (KDIM / 8) /* 512 packed dwords per n-row */
#define NGRP 32

typedef const __attribute__((address_space(1))) void* gas_ptr;
typedef __attribute__((address_space(3))) void* las_ptr;

__device__ __forceinline__ unsigned short f2bf(float f) {
  union { float f; unsigned int u; } v;
  v.f = f;
  unsigned int r = v.u + 0x7FFFu + ((v.u >> 16) & 1u); // RNE
  return (unsigned short)(r >> 16);
}

__device__ __forceinline__ void gl_lds16(const void* g, void* l) {
  __builtin_amdgcn_global_load_lds((gas_ptr)g, (las_ptr)l, 16, 0, 0);
}

// ---- prep: pack q nibbles (64->8 MB) + A fp32->bf16 + zero d_out ----------
#define SEG0 (NDIM * KP8)             /* 2097152 pack threads */
#define SEG1 (SEG0 + MDIM * KDIM / 4) /* +262144 A-conv */
#define SEG2 (SEG1 + MDIM * NDIM / 4) /* +262144 out-zero -> 2621440 = 10240*256 */
__global__ void prep_kernel(const float* __restrict__ A, const int* __restrict__ q,
                            unsigned short* __restrict__ Ab,
                            unsigned int* __restrict__ qp,
                            float* __restrict__ out) {
  int i = blockIdx.x * 256 + threadIdx.x;
  if (i < SEG0) { // 32B in / 4B out
    const int4* p = reinterpret_cast<const int4*>(q) + (size_t)i * 2;
    int4 a = p[0], b = p[1];
    unsigned int d = (unsigned)(a.x & 15) | ((unsigned)(a.y & 15) << 4) |
                     ((unsigned)(a.z & 15) << 8) | ((unsigned)(a.w & 15) << 12) |
                     ((unsigned)(b.x & 15) << 16) | ((unsigned)(b.y & 15) << 20) |
                     ((unsigned)(b.z & 15) << 24) | ((unsigned)(b.w & 15) << 28);
    qp[i] = d;
  } else if (i < SEG1) {
    int j = i - SEG0;
    float4 v = reinterpret_cast<const float4*>(A)[j];
    ushort4 o;
    o.x = f2bf(v.x); o.y = f2bf(v.y); o.z = f2bf(v.z); o.w = f2bf(v.w);
    reinterpret_cast<ushort4*>(Ab)[j] = o;
  } else {
    int j = i - SEG1;
    reinterpret_cast<float4*>(out)[j] = make_float4(0.f, 0.f, 0.f, 0.f);
  }
}

// ---- GEMM: BM=64, BN=128, BK=64, 4 waves, 2 blocks/CU, SPLITK=4 -----------
// Staged-byte-minimal geometry (A 64 MB + q 32 MB). Scales in LDS (proven
// R7/R8 pattern) with an explicit vmcnt(0) fence after scale staging so the
// hand vmcnt ledger counts ONLY pipeline ops. Ledger: 3 vmem/batch (1 q int4
// + 2 gl_lds), 3 batches in flight, drain vmcnt(6), never 0 in the loop.
#define BM 64
#define BN 128
#define BK 64
#define SPLITK 4
#define KLOC (KDIM / SPLITK) /* 1024 */
#define NTL (KLOC / BK)      /* 16 */
#define GPS (KLOC / 128)     /* 8 groups per split */

__global__ __launch_bounds__(256, 2) void gemm_v10(
    const unsigned short* __restrict__ Ab, const unsigned int* __restrict__ qp,
    const float* __restrict__ sc, const float* __restrict__ zr,
    float* __restrict__ out) {
  __shared__ __align__(16) unsigned short A_lds[4][BM * BK]; // 4 x 8 KB
  __shared__ __align__(16) unsigned short W_lds[2][BN * BK]; // 2 x 16 KB
  __shared__ float s_lds[BN * GPS];   // 4 KB
  __shared__ float zs_lds[BN * GPS];  // 4 KB  -> total 72 KB, 2 blocks/CU

  const int tid = threadIdx.x;
  const int lane = tid & 63;
  const int wave = tid >> 6;   // 0..3
  const int wm = wave >> 1;    // 0..1 -> 32 rows each
  const int wn = wave & 1;     // 0..1 -> 64 cols each

  // XCD decode: both blocks-pairs of an XCD share one q k-slice (2 MB) and
  // 2 A strips (256 KB) -> per-XCD L2 working set ~2.3 MB.
  const int bid = blockIdx.x;       // 512
  const int xcd = bid & 7;
  const int j = bid >> 3;           // 0..63
  const int sl = j >> 5;            // 0..1
  const int nl = j & 31;            // n-range
  const int sid = xcd * 2 + sl;     // 0..15
  const int m0 = (sid & 3) * BM;
  const int ks = sid >> 2;          // 0..3
  const int n0 = nl * BN;
  const int kbase = ks * KLOC;

  // ---- stage (s, z*s) into LDS: 128 rows x 8 groups = 1024, 4 passes ----
  for (int i = tid; i < BN * GPS; i += 256) {
    int n = i >> 3;
    int g = i & 7;
    float s = sc[(size_t)(n0 + n) * NGRP + ks * GPS + g];
    float z = zr[(size_t)(n0 + n) * NGRP + ks * GPS + g];
    s_lds[i] = s;
    zs_lds[i] = z * s;
  }
  // ledger-clean fence: ALL scale vmem + ds ops drained before pipeline issues
  asm volatile("s_waitcnt vmcnt(0) lgkmcnt(0)" ::: "memory");
  __builtin_amdgcn_sched_barrier(0);

  const unsigned short* Abase = Ab + (size_t)m0 * KDIM + kbase;
  const int wrow = tid >> 1; // 0..127 (n-row for W staging)
  const int wc = tid & 1;    // which int4 (32 nibbles) within 64-k row
  const int4* qpbase = reinterpret_cast<const int4*>(
      qp + (size_t)(n0 + wrow) * KP8 + (kbase >> 3)) + wc;

  int4 qr[4];

  auto loadW = [&](int t, int idx) { qr[idx] = qpbase[t * 2]; };
  // A tile 64x64 bf16 = 512 x 16B chunks; 256 threads x 2 gl_lds.
  // Linear LDS dest; XOR-swizzled global SOURCE (rule 21).
  auto stageA = [&](int t, int b) {
#pragma unroll
    for (int i = 0; i < 2; ++i) {
      int cid = i * 256 + tid;
      int row = cid >> 3;
      int cp = cid & 7;
      int cs = cp ^ (row & 7);
      const unsigned short* g = Abase + (size_t)row * KDIM + t * BK + cs * 8;
      gl_lds16(g, &A_lds[b][(i * 256 + wave * 64) * 8]); // wave-uniform base
    }
  };
  // dequant 32 nibbles -> 4 bf16x8 -> swizzled ds_write_b128
  auto writeW = [&](int t, int b, int idx) {
    int gg = t >> 1; // local group (BK=64, group=128)
    float s = s_lds[wrow * GPS + gg];
    float zs = zs_lds[wrow * GPS + gg];
    unsigned int dw[4] = {(unsigned)qr[idx].x, (unsigned)qr[idx].y,
                          (unsigned)qr[idx].z, (unsigned)qr[idx].w};
#pragma unroll
    for (int c = 0; c < 4; ++c) {
      unsigned int d = dw[c];
      bf16x8 w;
#pragma unroll
      for (int e = 0; e < 8; ++e)
        w[e] = (short)f2bf(fmaf((float)((d >> (4 * e)) & 15u), s, -zs));
      *reinterpret_cast<bf16x8*>(
          &W_lds[b][wrow * BK + (((wc * 4 + c) ^ (wrow & 7)) << 3)]) = w;
    }
  };

  f32x4 acc[2][4];
#pragma unroll
  for (int i = 0; i < 2; ++i)
#pragma unroll
    for (int n = 0; n < 4; ++n) acc[i][n] = (f32x4){0.f, 0.f, 0.f, 0.f};

  const int l15 = lane & 15;
  const int lhi = lane >> 4;
  const int ar0 = wm * 32 + l15; // 0..47 (+mi*16 -> 0..63)
  const int asw = ar0 & 7;
  const int bsw = l15 & 7; // (wn*64 + ni*16 + l15) & 7 == l15 & 7

  auto compute = [&](int ab, int wb) {
#pragma unroll
    for (int kss = 0; kss < 2; ++kss) {
      bf16x8 afr[2];
#pragma unroll
      for (int mi = 0; mi < 2; ++mi)
        afr[mi] = *reinterpret_cast<const bf16x8*>(
            &A_lds[ab][(ar0 + mi * 16) * BK + ((((kss << 2) + lhi) ^ asw) << 3)]);
#pragma unroll
      for (int ni = 0; ni < 4; ++ni) {
        const int br = wn * 64 + ni * 16 + l15;
        bf16x8 bfr = *reinterpret_cast<const bf16x8*>(
            &W_lds[wb][br * BK + ((((kss << 2) + lhi) ^ bsw) << 3)]);
#pragma unroll
        for (int mi = 0; mi < 2; ++mi)
          acc[mi][ni] = __builtin_amdgcn_mfma_f32_16x16x32_bf16(
              afr[mi], bfr, acc[mi][ni], 0, 0, 0);
      }
    }
  };

  // ---- prologue: 3 batches in flight (3 vmem each) ----
  loadW(0, 0); stageA(0, 0);
  loadW(1, 1); stageA(1, 1);
  loadW(2, 2); stageA(2, 2);

  __builtin_amdgcn_s_barrier();       // s_lds/zs_lds visible to all waves
  __builtin_amdgcn_sched_barrier(0);
  writeW(0, 0, 0);                    // compiler inserts precise vmcnt for qr[0]
  asm volatile("s_waitcnt vmcnt(6) lgkmcnt(0)" ::: "memory"); // batch0 done
  __builtin_amdgcn_s_barrier();       // A(0), W(0) ready
  __builtin_amdgcn_sched_barrier(0);

  // ---- main loop: NTL=16, unroll-4, 3-ahead, never drain vmcnt to 0 ----
  for (int tb = 0; tb < NTL; tb += 4) {
#pragma unroll
    for (int u = 0; u < 4; ++u) {
      const int t = tb + u;
      const int tp = (t + 3 < NTL) ? (t + 3) : 0; // dummy keeps counts exact
      loadW(tp, (u + 3) & 3);
      stageA(tp, (u + 3) & 3);
      compute(u & 3, u & 1);
      if (t + 1 < NTL) writeW(t + 1, (u + 1) & 1, (u + 1) & 3);
      asm volatile("s_waitcnt vmcnt(6) lgkmcnt(0)" ::: "memory"); // drain t+1
      __builtin_amdgcn_s_barrier();
      __builtin_amdgcn_sched_barrier(0);
    }
  }

  // epilogue: D col=lane&15 (+ni*16), row=4*lhi+jj (+mi*16); split-K adds
  const int col = n0 + wn * 64 + l15;
  const int rb = m0 + wm * 32 + (lhi << 2);
#pragma unroll
  for (int mi = 0; mi < 2; ++mi)
#pragma unroll
    for (int ni = 0; ni < 4; ++ni)
#pragma unroll
      for (int jj = 0; jj < 4; ++jj)
        unsafeAtomicAdd(&out[(size_t)(rb + mi * 16 + jj) * NDIM + col + ni * 16],
                        acc[mi][ni][jj]);
}

// ---------------- fallback (ws too small): exact R3-proven path --------------
#define FBM 128
#define FBN 32
#define FSPLITK 2
#define FKLOC (KDIM / FSPLITK)
#define FNTL (FKLOC / BK)

__global__ void convA_kernel(const float* __restrict__ A,
                             unsigned short* __restrict__ Ab) {
  int i = blockIdx.x * 256 + threadIdx.x;
  float4 v = reinterpret_cast<const float4*>(A)[i];
  ushort4 o;
  o.x = f2bf(v.x); o.y = f2bf(v.y); o.z = f2bf(v.z); o.w = f2bf(v.w);
  reinterpret_cast<ushort4*>(Ab)[i] = o;
}

__global__ __launch_bounds__(256, 2) void gemm_r3(
    const unsigned short* __restrict__ Ab, const int* __restrict__ qw,
    const float* __restrict__ sc, const float* __restrict__ zr,
    float* __restrict__ out) {
  __shared__ __align__(16) unsigned short A_lds[4][FBM * BK];
  __shared__ __align__(16) unsigned short W_lds[2][FBN * BK];
  __shared__ float s_lds[FBN * 16];
  __shared__ float zs_lds[FBN * 16];

  const int tid = threadIdx.x;
  const int lane = tid & 63;
  const int wave = tid >> 6;
  const int wm = wave >> 1;
  const int wn = wave & 1;

  const int bid = blockIdx.x;
  const int x = bid & 7;
  const int j = bid >> 3;
  const int r = x * 16 + (j >> 2);
  const int c = j & 3;
  const int m0 = (c & 1) * FBM;
  const int ks = c >> 1;
  const int n0 = r * FBN;

  for (int i = tid; i < FBN * 16; i += 256) {
    int n = i >> 4;
    int g16 = i & 15;
    float s = sc[(size_t)(n0 + n) * NGRP + ks * 16 + g16];
    float z = zr[(size_t)(n0 + n) * NGRP + ks * 16 + g16];
    s_lds[i] = s;
    zs_lds[i] = z * s;
  }

  const unsigned short* Abase = Ab + (size_t)m0 * KDIM + ks * FKLOC;
  const int wrow = tid >> 3;
  const int wc = tid & 7;
  const int* qbase = qw + (size_t)(n0 + wrow) * KDIM + ks * FKLOC + wc * 8;

  int4 qr[4][2];

  auto loadW = [&](int t, int idx) {
    const int* p = qbase + t * BK;
    qr[idx][0] = *reinterpret_cast<const int4*>(p);
    qr[idx][1] = *reinterpret_cast<const int4*>(p + 4);
  };
  auto stageA = [&](int t, int b) {
#pragma unroll
    for (int i = 0; i < 4; ++i) {
      int cid = i * 256 + tid;
      int row = cid >> 3;
      int cp = cid & 7;
      int cs = cp ^ (row & 7);
      const unsigned short* g = Abase + (size_t)row * KDIM + t * BK + cs * 8;
      gl_lds16(g, &A_lds[b][(i * 256 + wave * 64) * 8]);
    }
  };
  auto writeW = [&](int t, int b, int idx) {
    int gg = t >> 1;
    float s = s_lds[wrow * 16 + gg];
    float zs = zs_lds[wrow * 16 + gg];
    int q[8] = {qr[idx][0].x, qr[idx][0].y, qr[idx][0].z, qr[idx][0].w,
                qr[idx][1].x, qr[idx][1].y, qr[idx][1].z, qr[idx][1].w};
    bf16x8 w;
#pragma unroll
    for (int jj = 0; jj < 8; ++jj)
      w[jj] = (short)f2bf(fmaf((float)q[jj], s, -zs));
    *reinterpret_cast<bf16x8*>(
        &W_lds[b][wrow * BK + ((wc ^ (wrow & 7)) << 3)]) = w;
  };

  f32x4 acc[4];
#pragma unroll
  for (int i = 0; i < 4; ++i) acc[i] = (f32x4){0.f, 0.f, 0.f, 0.f};

  const int l15 = lane & 15;
  const int lhi = lane >> 4;
  const int ar0 = wm * 64 + l15;
  const int asw = ar0 & 7;
  const int br = wn * 16 + l15;
  const int bsw = br & 7;

  auto compute = [&](int ab, int wb) {
#pragma unroll
    for (int kss = 0; kss < 2; ++kss) {
      bf16x8 bfr = *reinterpret_cast<const bf16x8*>(
          &W_lds[wb][br * BK + ((((kss << 2) + lhi) ^ bsw) << 3)]);
#pragma unroll
      for (int mi = 0; mi < 4; ++mi) {
        bf16x8 afr = *reinterpret_cast<const bf16x8*>(
            &A_lds[ab][(ar0 + mi * 16) * BK + ((((kss << 2) + lhi) ^ asw) << 3)]);
        acc[mi] = __builtin_amdgcn_mfma_f32_16x16x32_bf16(afr, bfr, acc[mi], 0, 0, 0);
      }
    }
  };

  loadW(0, 0); stageA(0, 0);
  loadW(1, 1); stageA(1, 1);
  loadW(2, 2); stageA(2, 2);

  asm volatile("s_waitcnt lgkmcnt(0)" ::: "memory");
  __builtin_amdgcn_s_barrier();
  __builtin_amdgcn_sched_barrier(0);
  writeW(0, 0, 0);
  asm volatile("s_waitcnt vmcnt(12) lgkmcnt(0)" ::: "memory");
  __builtin_amdgcn_s_barrier();
  __builtin_amdgcn_sched_barrier(0);

  for (int tb = 0; tb < FNTL; tb += 4) {
#pragma unroll
    for (int u = 0; u < 4; ++u) {
      const int t = tb + u;
      const int tp = (t + 3 < FNTL) ? (t + 3) : 0;
      loadW(tp, (u + 3) & 3);
      stageA(tp, (u + 3) & 3);
      compute(u, u & 1);
      if (t + 1 < FNTL) writeW(t + 1, (u + 1) & 1, (u + 1) & 3);
      asm volatile("s_waitcnt vmcnt(12) lgkmcnt(0)" ::: "memory");
      __builtin_amdgcn_s_barrier();
      __builtin_amdgcn_sched_barrier(0);
    }
  }

  const int col = n0 + wn * 16 + l15;
  const int rb = m0 + wm * 64 + (lhi << 2);
#pragma unroll
  for (int mi = 0; mi < 4; ++mi)
#pragma unroll
    for (int jj = 0; jj < 4; ++jj)
      unsafeAtomicAdd(&out[(size_t)(rb + mi * 16 + jj) * NDIM + col],
                      acc[mi][jj]);
}

extern "C" void kernel_launch(void* const* d_in, const int* in_sizes, int n_in,
                              void* d_out, int out_size, void* d_ws, size_t ws_size,
                              hipStream_t stream) {
  const float* A = (const float*)d_in[0];
  const int* qw = (const int*)d_in[1];
  const float* sc = (const float*)d_in[2];
  const float* zr = (const float*)d_in[3];
  float* out = (float*)d_out;

  if (ws_size >= (10u << 20)) {
    // packed path: Ab 2MB @0, qp 8MB @2MB (ws verified 256 MiB on this rig)
    unsigned short* Ab = (unsigned short*)d_ws;
    unsigned int* qp = (unsigned int*)((char*)d_ws + (2u << 20));
    prep_kernel<<<10240, 256, 0, stream>>>(A, qw, Ab, qp, out); // also zeroes out
    gemm_v10<<<(MDIM / BM) * (NDIM / BN) * SPLITK, 256, 0, stream>>>(
        Ab, qp, sc, zr, out);
  } else {
    // fallback: exact R3-proven path (needs only 2MB)
    hipMemsetAsync(d_out, 0, (size_t)MDIM * NDIM * sizeof(float), stream);
    unsigned short* Ab = (unsigned short*)d_ws;
    convA_kernel<<<(MDIM * KDIM / 4) / 256, 256, 0, stream>>>(A, Ab);
    gemm_r3<<<(MDIM / FBM) * (NDIM / FBN) * FSPLITK, 256, 0, stream>>>(
        Ab, qw, sc, zr, out);
  }
}

// Round 11
// 127.053 us; speedup vs baseline: 1.0587x; 1.0587x over previous
//
#include <hip/hip_runtime.h>

typedef __attribute__((ext_vector_type(8))) short bf16x8;
typedef __attribute__((ext_vector_type(4))) float f32x4;

#define MDIM 256
#define NDIM 4096
#define KDIM 4096
#define NGRP 32

typedef const __attribute__((address_space(1))) void* gas_ptr;
typedef __attribute__((address_space(3))) void* las_ptr;

__device__ __forceinline__ unsigned short f2bf(float f) {
  union { float f; unsigned int u; } v;
  v.f = f;
  unsigned int r = v.u + 0x7FFFu + ((v.u >> 16) & 1u); // RNE
  return (unsigned short)(r >> 16);
}

__device__ __forceinline__ void gl_lds16(const void* g, void* l) {
  __builtin_amdgcn_global_load_lds((gas_ptr)g, (las_ptr)l, 16, 0, 0);
}

// A fp32 -> bf16 (4 MB -> 2 MB); 262144 threads
__global__ void convA_kernel(const float* __restrict__ A,
                             unsigned short* __restrict__ Ab) {
  int i = blockIdx.x * 256 + threadIdx.x;
  float4 v = reinterpret_cast<const float4*>(A)[i];
  ushort4 o;
  o.x = f2bf(v.x); o.y = f2bf(v.y); o.z = f2bf(v.z); o.w = f2bf(v.w);
  reinterpret_cast<ushort4*>(Ab)[i] = o;
}

// ---- GEMM: R8-proven frame (BM=256, BN=64, BK=64, 8 waves, 1 block/CU,
// SPLITK=4) with RAW q streamed in-kernel (M/BM=1 -> q read exactly once;
// the pack prepass buys nothing for this geometry and its 11us is deleted).
// q path (loadW 2x int4 + writeW unpack) and the 6-vmem/batch vmcnt(12)
// ledger are verbatim from the R3/R7-passing kernels.
#define BM 256
#define BN 64
#define BK 64
#define SPLITK 4
#define KLOC (KDIM / SPLITK) /* 1024 */
#define NTL (KLOC / BK)      /* 16 */
#define GPS (KLOC / 128)     /* 8 groups per split */

__global__ __launch_bounds__(512, 1) void gemm_raw(
    const unsigned short* __restrict__ Ab, const int* __restrict__ qw,
    const float* __restrict__ sc, const float* __restrict__ zr,
    float* __restrict__ out) {
  __shared__ __align__(16) unsigned short A_lds[4][BM * BK]; // 4 x 32 KB
  __shared__ __align__(16) unsigned short W_lds[2][BN * BK]; // 2 x 8 KB
  __shared__ float s_lds[BN * GPS];   // 2 KB
  __shared__ float zs_lds[BN * GPS];  // 2 KB   total 148 KB -> 1 block/CU

  const int tid = threadIdx.x;
  const int lane = tid & 63;
  const int wave = tid >> 6;      // 0..7
  const int wm = wave >> 1;       // 0..3 -> 64 rows each
  const int wn = wave & 1;        // 0..1 -> 32 cols each

  // XCD swizzle: grid 256; each XCD gets 8 n-ranges x 4 k-splits. A slices
  // (512 KB per ks) are co-XCD-shared; raw q is read-once streaming.
  const int bid = blockIdx.x;
  const int xcd = bid & 7;
  const int j = bid >> 3;        // 0..31
  const int ks = j >> 3;         // 0..3
  const int nl = j & 7;
  const int n0 = (xcd * 8 + nl) * BN; // 0..4032
  const int kbase = ks * KLOC;

  // stage (s, z*s): 64 rows x 8 groups = 512 = exactly one pass
  {
    int n = tid >> 3, g = tid & 7;
    float s = sc[(size_t)(n0 + n) * NGRP + ks * GPS + g];
    float z = zr[(size_t)(n0 + n) * NGRP + ks * GPS + g];
    s_lds[tid] = s;
    zs_lds[tid] = z * s;
  }

  const unsigned short* Abase = Ab + kbase;
  const int wrow = tid >> 3; // 0..63 (n-row for W staging)
  const int wc = tid & 7;    // 8-value k-chunk within 64-k row
  const int* qbase = qw + (size_t)(n0 + wrow) * KDIM + kbase + wc * 8;

  int4 qr[4][2]; // [slot][half]; indices literal after unroll (rule #20)

  auto loadW = [&](int t, int idx) {
    const int* p = qbase + t * BK;
    qr[idx][0] = *reinterpret_cast<const int4*>(p);
    qr[idx][1] = *reinterpret_cast<const int4*>(p + 4);
  };
  // A tile 256x64 bf16 = 2048 x 16B chunks; 512 threads x 4 gl_lds.
  // Linear LDS dest; XOR-swizzled global SOURCE (rule 21).
  auto stageA = [&](int t, int b) {
#pragma unroll
    for (int i = 0; i < 4; ++i) {
      int cid = i * 512 + tid;
      int row = cid >> 3;
      int cp = cid & 7;
      int cs = cp ^ (row & 7);
      const unsigned short* g = Abase + (size_t)row * KDIM + t * BK + cs * 8;
      gl_lds16(g, &A_lds[b][(i * 512 + wave * 64) * 8]); // wave-uniform base
    }
  };
  auto writeW = [&](int t, int b, int idx) {
    int gg = t >> 1; // BK=64: tile t in local group t>>1
    float s = s_lds[wrow * GPS + gg];
    float zs = zs_lds[wrow * GPS + gg];
    int q[8] = {qr[idx][0].x, qr[idx][0].y, qr[idx][0].z, qr[idx][0].w,
                qr[idx][1].x, qr[idx][1].y, qr[idx][1].z, qr[idx][1].w};
    bf16x8 w;
#pragma unroll
    for (int jj = 0; jj < 8; ++jj)
      w[jj] = (short)f2bf(fmaf((float)q[jj], s, -zs));
    *reinterpret_cast<bf16x8*>(
        &W_lds[b][wrow * BK + ((wc ^ (wrow & 7)) << 3)]) = w;
  };

  f32x4 acc[4][2];
#pragma unroll
  for (int i = 0; i < 4; ++i)
#pragma unroll
    for (int n = 0; n < 2; ++n) acc[i][n] = (f32x4){0.f, 0.f, 0.f, 0.f};

  const int l15 = lane & 15;
  const int lhi = lane >> 4;
  const int ar0 = wm * 64 + l15;  // 0..255
  const int asw = ar0 & 7;

  auto compute = [&](int ab, int wb) {
#pragma unroll
    for (int kss = 0; kss < 2; ++kss) {
#pragma unroll
      for (int ni = 0; ni < 2; ++ni) {
        const int br = wn * 32 + ni * 16 + l15; // 0..63
        bf16x8 bfr = *reinterpret_cast<const bf16x8*>(
            &W_lds[wb][br * BK + ((((kss << 2) + lhi) ^ (br & 7)) << 3)]);
#pragma unroll
        for (int mi = 0; mi < 4; ++mi) {
          bf16x8 afr = *reinterpret_cast<const bf16x8*>(
              &A_lds[ab][(ar0 + mi * 16) * BK +
                         ((((kss << 2) + lhi) ^ asw) << 3)]);
          acc[mi][ni] = __builtin_amdgcn_mfma_f32_16x16x32_bf16(
              afr, bfr, acc[mi][ni], 0, 0, 0);
        }
      }
    }
  };

  // prologue: 3 batches in flight (6 vmem each: 2 q int4 + 4 gl_lds)
  loadW(0, 0); stageA(0, 0);
  loadW(1, 1); stageA(1, 1);
  loadW(2, 2); stageA(2, 2);

  asm volatile("s_waitcnt lgkmcnt(0)" ::: "memory"); // s/zs stores done
  __builtin_amdgcn_s_barrier();
  __builtin_amdgcn_sched_barrier(0);
  writeW(0, 0, 0); // compiler inserts precise vmcnt for qr[0]
  asm volatile("s_waitcnt vmcnt(12) lgkmcnt(0)" ::: "memory"); // batch0 done
  __builtin_amdgcn_s_barrier();
  __builtin_amdgcn_sched_barrier(0);

  // main loop: NTL=16, unroll-4, 3-ahead issue, never drain vmcnt to 0
  for (int tb = 0; tb < NTL; tb += 4) {
#pragma unroll
    for (int u = 0; u < 4; ++u) {
      const int t = tb + u;
      const int tp = (t + 3 < NTL) ? (t + 3) : 0; // dummy keeps counts exact
      loadW(tp, (u + 3) & 3);
      stageA(tp, (u + 3) & 3);
      compute(u, u & 1);
      if (t + 1 < NTL) writeW(t + 1, (u + 1) & 1, (u + 1) & 3);
      asm volatile("s_waitcnt vmcnt(12) lgkmcnt(0)" ::: "memory");
      __builtin_amdgcn_s_barrier();
      __builtin_amdgcn_sched_barrier(0);
    }
  }

  // epilogue: D col=lane&15 (+ni*16), row=4*lhi+j (+mi*16); split-K atomic add
  const int col = n0 + wn * 32 + l15;
  const int rb = wm * 64 + (lhi << 2);
#pragma unroll
  for (int mi = 0; mi < 4; ++mi)
#pragma unroll
    for (int ni = 0; ni < 2; ++ni)
#pragma unroll
      for (int jj = 0; jj < 4; ++jj)
        unsafeAtomicAdd(&out[(size_t)(rb + mi * 16 + jj) * NDIM + col + ni * 16],
                        acc[mi][ni][jj]);
}

extern "C" void kernel_launch(void* const* d_in, const int* in_sizes, int n_in,
                              void* d_out, int out_size, void* d_ws, size_t ws_size,
                              hipStream_t stream) {
  const float* A = (const float*)d_in[0];
  const int* qw = (const int*)d_in[1];
  const float* sc = (const float*)d_in[2];
  const float* zr = (const float*)d_in[3];
  float* out = (float*)d_out;
  unsigned short* Ab = (unsigned short*)d_ws; // 2 MB bf16 copy of A

  hipMemsetAsync(d_out, 0, (size_t)MDIM * NDIM * sizeof(float), stream);
  convA_kernel<<<(MDIM * KDIM / 4) / 256, 256, 0, stream>>>(A, Ab);
  gemm_raw<<<(NDIM / BN) * SPLITK, 512, 0, stream>>>(Ab, qw, sc, zr, out);
}